// Round 3
// baseline (5296.726 us; speedup 1.0000x reference)
//
#include <hip/hip_runtime.h>
#include <hip/hip_fp16.h>

#define BB 128
#define TT 500
#define HH 512
#define TWOH 1024
#define KB 16  // k-tiles of 32

typedef _Float16 f16x8 __attribute__((ext_vector_type(8)));
typedef float f32x4 __attribute__((ext_vector_type(4)));

// workspace: u16 (1 MiB) | hx u32 [8 groups][2 parity][16 m][512 k] (512 KiB)
#define WS_U16_HALVES (TWOH * HH)
#define HX_WORDS (8 * 2 * 16 * 512)

__global__ void prep_kernel(const float* __restrict__ u,
                            const float* __restrict__ ht,
                            __half* __restrict__ u16,
                            unsigned* __restrict__ hx) {
  int i = blockIdx.x * blockDim.x + threadIdx.x;
  if (i < WS_U16_HALVES) u16[i] = __float2half(u[i]);
  if (i < HX_WORDS) {
    int g = i >> 14, rem = i & 16383;
    int par = rem >> 13, mk = rem & 8191;
    int m = mk >> 9, k = mk & 511;
    unsigned val;
    if (par == 0) {  // h_0 tagged 0
      int R = g * 16 + m;
      val = (unsigned)__half_as_ushort(__float2half(ht[(size_t)R * HH + k]));
    } else {
      val = 0xFFFF0000u;  // never matches a step tag (kills replay staleness)
    }
    hx[i] = val;
  }
}

// 32 blocks x 256 threads. Block b: col-slice s=b>>2 (64 cols) for groups
// gA=2*(b&3) and gB=gA+1 (independent recurrence chains, interleaved so the
// cross-XCD h propagation of one group hides under the other's compute).
// Wave w owns cols j0=s*64+w*16; lane holds BOTH gate tiles for col j0+l15.
__global__ __launch_bounds__(256, 1) void ligru_mfma(
    const float* __restrict__ wx, const __half* __restrict__ u16,
    const float* __restrict__ ht, const float* __restrict__ mask,
    float* __restrict__ out, unsigned* __restrict__ hx) {
  const int tid = threadIdx.x;
  const int lane = tid & 63;
  const int w = tid >> 6;
  const int l15 = lane & 15;
  const int q = lane >> 4;
  const int b = blockIdx.x;
  const int s = b >> 2;
  const int gI[2] = {(b & 3) * 2, (b & 3) * 2 + 1};
  const int row0[2] = {gI[0] * 16, gI[1] * 16};

  const int j0 = s * 64 + w * 16;
  const int j = j0 + l15;

  __shared__ alignas(16) char h16[2][16 * 1024];  // [G][m][k] fp16, XOR-swz

  // B-frags (u), persistent in VGPRs, shared by both groups (same cols).
  // nt=0: gate row j (at); nt=1: gate row 512+j (zt).
  f16x8 bf[KB][2];
#pragma unroll
  for (int kb = 0; kb < KB; ++kb) {
    bf[kb][0] = *(const f16x8*)(u16 + (size_t)j * HH + kb * 32 + q * 8);
    bf[kb][1] = *(const f16x8*)(u16 + (size_t)(HH + j) * HH + kb * 32 + q * 8);
  }

  // per-lane persistent state: rows m=4q+r, col j, fp32 master h
  float hreg[2][4], mreg[2][4];
#pragma unroll
  for (int G = 0; G < 2; ++G)
#pragma unroll
    for (int r = 0; r < 4; ++r) {
      size_t off = (size_t)(row0[G] + 4 * q + r) * HH + j;
      mreg[G][r] = mask[off];
      hreg[G][r] = ht[off];
    }

  const size_t BTH = (size_t)BB * TT * HH;
  float* out_h = out;
  float* out_z = out + BTH;
  float* out_a = out + 2 * BTH;
  float* out_hc = out + 3 * BTH;

  const int mrow = tid >> 4;        // LDS row this thread stages
  const int kc0 = (tid & 15) * 32;  // first half-index within the row

  for (int t = 0; t < TT; ++t) {
    // wx prefetch (h-independent; overlaps the first poll)
    float wxa[2][4], wxz[2][4];
#pragma unroll
    for (int G = 0; G < 2; ++G)
#pragma unroll
      for (int r = 0; r < 4; ++r) {
        size_t base = ((size_t)(row0[G] + 4 * q + r) * TT + t) * TWOH + j;
        wxa[G][r] = wx[base];
        wxz[G][r] = wx[base + HH];
      }

#pragma unroll
    for (int G = 0; G < 2; ++G) {
      // ---- phase 1: poll tagged h_t words (flag fused with data)
      unsigned* src = hx + gI[G] * 16384 + (t & 1) * 8192 + tid * 32;
      unsigned v[32];
      int bail = 0;
      bool ok;
      do {
        ok = true;
#pragma unroll
        for (int p = 0; p < 32; ++p)
          v[p] = __hip_atomic_load(src + p, __ATOMIC_RELAXED,
                                   __HIP_MEMORY_SCOPE_AGENT);
#pragma unroll
        for (int p = 0; p < 32; ++p) ok &= ((v[p] >> 16) == (unsigned)t);
        if (!ok) __builtin_amdgcn_s_sleep(1);
      } while (!ok && ++bail < (1 << 20));

      // ---- stage into LDS (pack 4 halves -> b64, row-XOR swizzle)
      {
        char* dst = h16[G];
        int byte0 = mrow * 1024 + kc0 * 2;
        int swz = (mrow & 7) << 4;
#pragma unroll
        for (int c = 0; c < 8; ++c) {
          unsigned long long pk =
              (unsigned long long)(v[4 * c] & 0xFFFFu) |
              ((unsigned long long)(v[4 * c + 1] & 0xFFFFu) << 16) |
              ((unsigned long long)(v[4 * c + 2] & 0xFFFFu) << 32) |
              ((unsigned long long)(v[4 * c + 3] & 0xFFFFu) << 48);
          *(unsigned long long*)(dst + ((byte0 + c * 8) ^ swz)) = pk;
        }
      }
      __syncthreads();

      // ---- MFMA: A row=l15 (m), k-chunk q; both gate tiles
      f32x4 acc0 = {0.f, 0.f, 0.f, 0.f}, acc1 = {0.f, 0.f, 0.f, 0.f};
#pragma unroll
      for (int kb = 0; kb < KB; ++kb) {
        int off = (l15 * 1024 + kb * 64 + q * 16) ^ ((l15 & 7) << 4);
        f16x8 af = *(const f16x8*)(h16[G] + off);
        acc0 = __builtin_amdgcn_mfma_f32_16x16x32_f16(af, bf[kb][0], acc0, 0, 0, 0);
        acc1 = __builtin_amdgcn_mfma_f32_16x16x32_f16(af, bf[kb][1], acc1, 0, 0, 0);
      }

      // ---- epilogue: h stores FIRST (critical path), outputs after
      unsigned* hdst = hx + gI[G] * 16384 + ((t + 1) & 1) * 8192;
      const unsigned tagn = (unsigned)(t + 1) << 16;
      float atv[4], ztv[4], hcv[4];
#pragma unroll
      for (int r = 0; r < 4; ++r) {
        float at = acc0[r] + wxa[G][r];
        float ztp = acc1[r] + wxz[G][r];
        float zt = 1.f / (1.f + __expf(-ztp));
        float hc = fmaxf(at, 0.f) * mreg[G][r];
        float hn = hreg[G][r] * zt + (1.f - zt) * hc;
        hreg[G][r] = hn;
        __hip_atomic_store(hdst + (4 * q + r) * 512 + j,
                           tagn | (unsigned)__half_as_ushort(__float2half(hn)),
                           __ATOMIC_RELAXED, __HIP_MEMORY_SCOPE_AGENT);
        atv[r] = at;
        ztv[r] = zt;
        hcv[r] = hc;
      }
#pragma unroll
      for (int r = 0; r < 4; ++r) {
        size_t oidx = ((size_t)(row0[G] + 4 * q + r) * TT + t) * HH + j;
        out_h[oidx] = hreg[G][r];
        out_z[oidx] = ztv[r];
        out_a[oidx] = atv[r];
        out_hc[oidx] = hcv[r];
      }
      // next write to h16[G] happens only after every wave passes the
      // OTHER phase's __syncthreads -> no LDS WAR race.
    }
  }
}

extern "C" void kernel_launch(void* const* d_in, const int* in_sizes, int n_in,
                              void* d_out, int out_size, void* d_ws,
                              size_t ws_size, hipStream_t stream) {
  const float* wx = (const float*)d_in[0];
  const float* u = (const float*)d_in[1];
  const float* ht = (const float*)d_in[2];
  const float* mask = (const float*)d_in[3];
  float* out = (float*)d_out;

  __half* u16 = (__half*)d_ws;
  unsigned* hx = (unsigned*)(u16 + WS_U16_HALVES);

  hipLaunchKernelGGL(prep_kernel, dim3(2048), dim3(256), 0, stream, u, ht, u16,
                     hx);
  hipLaunchKernelGGL(ligru_mfma, dim3(32), dim3(256), 0, stream, wx, u16, ht,
                     mask, out, hx);
}

// Round 4
// 2935.311 us; speedup vs baseline: 1.8045x; 1.8045x over previous
//
#include <hip/hip_runtime.h>
#include <hip/hip_fp16.h>

#define BB 128
#define TT 500
#define HH 512
#define TWOH 1024
#define KB 16  // k-tiles of 32

typedef _Float16 f16x8 __attribute__((ext_vector_type(8)));
typedef float f32x4 __attribute__((ext_vector_type(4)));
typedef unsigned long long u64;

// workspace: u16 (1 MiB) | hx u64 [8 g][2 parity][16 m][256 k2] (512 KiB)
// hx word = (tag<<32) | (fp16 h[m][2*k2+1] <<16) | (fp16 h[m][2*k2])
#define WS_U16_HALVES (TWOH * HH)
#define HX_QWORDS (8 * 2 * 16 * 256)

__global__ void prep_kernel(const float* __restrict__ u,
                            const float* __restrict__ ht,
                            __half* __restrict__ u16, u64* __restrict__ hx) {
  int i = blockIdx.x * blockDim.x + threadIdx.x;
  if (i < WS_U16_HALVES) u16[i] = __float2half(u[i]);
  if (i < HX_QWORDS) {
    int g = i >> 13, rem = i & 8191;
    int par = rem >> 12, m = (rem >> 8) & 15, k2 = rem & 255;
    u64 val;
    if (par == 0) {  // h_0, tag 0
      int R = g * 16 + m;
      unsigned lo =
          (unsigned)__half_as_ushort(__float2half(ht[(size_t)R * HH + 2 * k2])) |
          ((unsigned)__half_as_ushort(
               __float2half(ht[(size_t)R * HH + 2 * k2 + 1]))
           << 16);
      val = (u64)lo;
    } else {
      val = 0xFFFFFFFF00000000ull;  // sentinel: never matches any step tag
    }
    hx[i] = val;
  }
}

// 128 blocks x 64 threads (1 wave, fully independent: no LDS, no barriers).
// Block b: col-slice s=b>>2 (16 cols), groups gA=2*(b&3), gB=gA+1 (independent
// chains interleaved to hide cross-XCD h propagation). Lane role: l15 = col
// offset (j = s*16+l15) and A-row m; q = lane>>4 = k-chunk / output row group.
// The tagged-qword poll doubles as the MFMA A-fragment load (lo dwords).
__global__ __launch_bounds__(64, 1) void ligru_mfma(
    const float* __restrict__ wx, const __half* __restrict__ u16,
    const float* __restrict__ ht, const float* __restrict__ mask,
    float* __restrict__ out, u64* __restrict__ hx) {
  const int lane = threadIdx.x;
  const int l15 = lane & 15;
  const int q = lane >> 4;
  const int b = blockIdx.x;
  const int p = b & 3;
  const int s = b >> 2;
  const int gI[2] = {2 * p, 2 * p + 1};
  const int row0[2] = {gI[0] * 16, gI[1] * 16};
  const int j = s * 16 + l15;

  // B-frags (u), persistent: 128 VGPR, shared by both groups.
  f16x8 bf[KB][2];
#pragma unroll
  for (int kb = 0; kb < KB; ++kb) {
    bf[kb][0] = *(const f16x8*)(u16 + (size_t)j * HH + kb * 32 + q * 8);
    bf[kb][1] = *(const f16x8*)(u16 + (size_t)(HH + j) * HH + kb * 32 + q * 8);
  }

  // persistent per-lane state: rows m=4q+r, col j; fp32 master h
  float hreg[2][4], mreg[2][4];
#pragma unroll
  for (int G = 0; G < 2; ++G)
#pragma unroll
    for (int r = 0; r < 4; ++r) {
      size_t off = (size_t)(row0[G] + 4 * q + r) * HH + j;
      mreg[G][r] = mask[off];
      hreg[G][r] = ht[off];
    }

  const size_t BTH = (size_t)BB * TT * HH;
  float* out_h = out;
  float* out_z = out + BTH;
  float* out_a = out + 2 * BTH;
  float* out_hc = out + 3 * BTH;

  for (int t = 0; t < TT; ++t) {
    // wx prefetch for both chains (h-independent, hides HBM latency)
    float wxa[2][4], wxz[2][4];
#pragma unroll
    for (int G = 0; G < 2; ++G)
#pragma unroll
      for (int r = 0; r < 4; ++r) {
        size_t base = ((size_t)(row0[G] + 4 * q + r) * TT + t) * TWOH + j;
        wxa[G][r] = wx[base];
        wxz[G][r] = wx[base + HH];
      }

#pragma unroll
    for (int G = 0; G < 2; ++G) {
      // ---- poll h_t: 64 tagged qwords == this lane's A-frags for all kb.
      // lane reads row m=l15, halves k = kb*32 + q*8 + [0,8) -> qwords
      // k2 = kb*16 + q*4 + c. Adjacent lanes (same m... same q span 16B):
      // per-instr footprint is dense 8B*64 within the 16 rows.
      const u64* src =
          hx + ((size_t)(gI[G] * 2 + (t & 1)) * 16 + l15) * 256 + q * 4;
      u64 qw[KB][4];
      int bail = 0;
      for (;;) {
        bool ok = true;
#pragma unroll
        for (int kb = 0; kb < KB; ++kb)
#pragma unroll
          for (int c = 0; c < 4; ++c) {
            qw[kb][c] = __hip_atomic_load(src + kb * 16 + c, __ATOMIC_RELAXED,
                                          __HIP_MEMORY_SCOPE_AGENT);
          }
#pragma unroll
        for (int kb = 0; kb < KB; ++kb)
#pragma unroll
          for (int c = 0; c < 4; ++c)
            ok &= ((unsigned)(qw[kb][c] >> 32) == (unsigned)t);
        if (__all(ok) || ++bail > (1 << 14)) break;
        __builtin_amdgcn_s_sleep(1);
      }

      // ---- MFMA: A = lo dwords (no unpack), both gate tiles
      f32x4 acc0 = {0.f, 0.f, 0.f, 0.f}, acc1 = {0.f, 0.f, 0.f, 0.f};
#pragma unroll
      for (int kb = 0; kb < KB; ++kb) {
        uint4 d = {(unsigned)qw[kb][0], (unsigned)qw[kb][1],
                   (unsigned)qw[kb][2], (unsigned)qw[kb][3]};
        f16x8 af = __builtin_bit_cast(f16x8, d);
        acc0 = __builtin_amdgcn_mfma_f32_16x16x32_f16(af, bf[kb][0], acc0, 0, 0, 0);
        acc1 = __builtin_amdgcn_mfma_f32_16x16x32_f16(af, bf[kb][1], acc1, 0, 0, 0);
      }

      // ---- epilogue: h stores first (critical path), outputs after
      u64* dstbase = hx + (size_t)(gI[G] * 2 + ((t + 1) & 1)) * 16 * 256;
      const u64 tagn = (u64)(unsigned)(t + 1) << 32;
      float atv[4], ztv[4], hcv[4];
#pragma unroll
      for (int r = 0; r < 4; ++r) {
        float at = acc0[r] + wxa[G][r];
        float ztp = acc1[r] + wxz[G][r];
        float zt = 1.f / (1.f + __expf(-ztp));
        float hc = fmaxf(at, 0.f) * mreg[G][r];
        float hn = hreg[G][r] * zt + (1.f - zt) * hc;
        hreg[G][r] = hn;
        float hn_nbr = __shfl_xor(hn, 1);  // col pair (j even, j odd)
        if ((l15 & 1) == 0) {
          unsigned lo = (unsigned)__half_as_ushort(__float2half(hn)) |
                        ((unsigned)__half_as_ushort(__float2half(hn_nbr)) << 16);
          __hip_atomic_store(dstbase + (4 * q + r) * 256 + (j >> 1), tagn | lo,
                             __ATOMIC_RELAXED, __HIP_MEMORY_SCOPE_AGENT);
        }
        atv[r] = at;
        ztv[r] = zt;
        hcv[r] = hc;
      }
#pragma unroll
      for (int r = 0; r < 4; ++r) {
        size_t oidx = ((size_t)(row0[G] + 4 * q + r) * TT + t) * HH + j;
        __builtin_nontemporal_store(hreg[G][r], &out_h[oidx]);
        __builtin_nontemporal_store(ztv[r], &out_z[oidx]);
        __builtin_nontemporal_store(atv[r], &out_a[oidx]);
        __builtin_nontemporal_store(hcv[r], &out_hc[oidx]);
      }
    }
  }
}

extern "C" void kernel_launch(void* const* d_in, const int* in_sizes, int n_in,
                              void* d_out, int out_size, void* d_ws,
                              size_t ws_size, hipStream_t stream) {
  const float* wx = (const float*)d_in[0];
  const float* u = (const float*)d_in[1];
  const float* ht = (const float*)d_in[2];
  const float* mask = (const float*)d_in[3];
  float* out = (float*)d_out;

  __half* u16 = (__half*)d_ws;
  u64* hx = (u64*)(u16 + WS_U16_HALVES);

  hipLaunchKernelGGL(prep_kernel, dim3(2048), dim3(256), 0, stream, u, ht, u16,
                     hx);
  hipLaunchKernelGGL(ligru_mfma, dim3(128), dim3(64), 0, stream, wx, u16, ht,
                     mask, out, hx);
}